// Round 8
// baseline (41.364 us; speedup 1.0000x reference)
//
#include <hip/hip_runtime.h>
#include <math.h>

namespace {
constexpr int B2v = 512;
constexpr int NR  = 49;     // regions per view
constexpr int NP  = 64;     // padded rows for MFMA tile
constexpr int Dv  = 256;    // feature dim
constexpr int KQ  = 128;    // queue K
constexpr float INV_TAU     = 25.0f;  // 1/0.04
constexpr float INV_TAU_STU = 10.0f;  // 1/0.1
}

typedef __attribute__((ext_vector_type(8))) short bf16x8;
typedef __attribute__((ext_vector_type(4))) float f32x4;

__device__ __forceinline__ float wave_max(float v) {
  for (int o = 32; o; o >>= 1) v = fmaxf(v, __shfl_xor(v, o));
  return v;
}
__device__ __forceinline__ float wave_sum(float v) {
  for (int o = 32; o; o >>= 1) v += __shfl_xor(v, o);
  return v;
}
__device__ __forceinline__ short f2bf(float x) {  // RNE fp32->bf16
  unsigned u = __float_as_uint(x);
  u = u + 0x7FFFu + ((u >> 16) & 1u);
  return (short)(u >> 16);
}
__device__ __forceinline__ float bf2f(unsigned short h) {
  return __uint_as_float(((unsigned)h) << 16);
}
// read-once stream load (nt: bypass cache allocation); 16B-aligned sources
__device__ __forceinline__ f32x4 ntld4(const float* p) {
  return __builtin_nontemporal_load(reinterpret_cast<const f32x4*>(p));
}

// ---------------------------------------------------------------------------
// kmain: one 512-thread block per teacher batch bt (student bs = bt ^ 256).
// 8 waves -> 16 waves/CU (4/SIMD) at 2 blocks/CU (LDS ~67 KB).
// Cache-path discipline: nt-loads for read-once streams (s_fea, s_region,
// t-fea side), nt-stores for write-once outputs (out_tr/out_tc); ONLY the
// t-region-side rows stay on the cached path (re-read by the loss gather).
// ---------------------------------------------------------------------------
__global__ __launch_bounds__(512, 4) void kmain(
    const float* __restrict__ s_cls_out,
    const float* __restrict__ s_region_out,
    const float* __restrict__ s_fea,
    const float* __restrict__ t_cls_out,
    const float* __restrict__ t_region_out,
    const float* __restrict__ t_fea,
    const float* __restrict__ queue_all,
    const float* __restrict__ queue_grid_all,
    const float* __restrict__ center,
    const float* __restrict__ center_grid,
    const int* __restrict__ concept_idx,
    const int* __restrict__ pos_idx,
    const unsigned char* __restrict__ uq,
    float* __restrict__ out_tc,
    float* __restrict__ out_tr,
    float* __restrict__ block_part) {
  __shared__ __align__(16) unsigned short sfb[NP * Dv];  // 32 KB bf16, swizzled
  __shared__ __align__(16) unsigned short tfb[NP * Dv];  // 32 KB
  __shared__ float stats[NR * 2];
  __shared__ float rinv[NP];
  __shared__ float cand_v[2][NP];
  __shared__ int   cand_m[2][NP];
  __shared__ float red[8];
  __shared__ float cls_s;

  const int bt = blockIdx.x, bs = bt ^ 256;
  const int tid = threadIdx.x, lane = tid & 63, wave = tid >> 6;

  // ---- hoisted scalar/index loads (issue first, consume later) ----
  const int ci = concept_idx[bt], pi = pos_idx[bt];
  const uint2 w2 = ((const uint2*)uq)[lane];  // 512 B, legal in both layouts
  const float* sfsrc = s_fea + (size_t)bs * NR * Dv;

  // (a1) stage s-side bf16 tile (uq-independent; nt loads, read-once)
  for (int q = tid; q < NP * 32; q += 512) {
    const int r = q >> 5, c = q & 31;
    const int dst = r * Dv + ((c ^ (r & 7)) << 3);
    bf16x8 pa = {0, 0, 0, 0, 0, 0, 0, 0};
    if (r < NR) {
      const float* ps = sfsrc + (size_t)r * Dv + c * 8;
      f32x4 s0 = ntld4(ps), s1 = ntld4(ps + 4);
      pa[0] = f2bf(s0.x); pa[1] = f2bf(s0.y); pa[2] = f2bf(s0.z); pa[3] = f2bf(s0.w);
      pa[4] = f2bf(s1.x); pa[5] = f2bf(s1.y); pa[6] = f2bf(s1.z); pa[7] = f2bf(s1.w);
    }
    *(bf16x8*)&sfb[dst] = pa;
  }

  // (b) s_region y rows -> registers (wave-interleaved n), lse per row
  f32x4 yv[7];
  float lsev[7];
#pragma unroll
  for (int j = 0; j < 7; j++) {
    const int n = wave + 8 * j;
    if (n < NR) {
      f32x4 y4 = ntld4(s_region_out + ((size_t)bs * NR + n) * Dv + lane * 4);
      y4.x *= INV_TAU_STU; y4.y *= INV_TAU_STU;
      y4.z *= INV_TAU_STU; y4.w *= INV_TAU_STU;
      float smax = wave_max(fmaxf(fmaxf(y4.x, y4.y), fmaxf(y4.z, y4.w)));
      float ssum = wave_sum(expf(y4.x - smax) + expf(y4.y - smax) +
                            expf(y4.z - smax) + expf(y4.w - smax));
      yv[j] = y4;
      lsev[j] = smax + logf(ssum);
    }
  }

  // ---- per-wave use_queue layout detection (no barrier, no LDS) ----
  const bool isbool = __any(((w2.x | w2.y) & 0xFFFFFF00u) != 0) != 0;
  const int uqv = isbool ? (int)uq[bt] : ((const int*)uq)[bt];
  const bool use = uqv != 0;
  const size_t qoff = (size_t)ci * KQ + (size_t)pi;
  const float* qg = queue_grid_all + qoff * (size_t)(2 * NR) * Dv;
  const float* tfsrc = use ? (qg + (size_t)NR * Dv) : (t_fea + (size_t)bt * NR * Dv);

  // (a2) stage t-side bf16 tile (nt loads, read-once)
  for (int q = tid; q < NP * 32; q += 512) {
    const int r = q >> 5, c = q & 31;
    const int dst = r * Dv + ((c ^ (r & 7)) << 3);
    bf16x8 pb = {0, 0, 0, 0, 0, 0, 0, 0};
    if (r < NR) {
      const float* pt = tfsrc + (size_t)r * Dv + c * 8;
      f32x4 t0 = ntld4(pt), t1 = ntld4(pt + 4);
      pb[0] = f2bf(t0.x); pb[1] = f2bf(t0.y); pb[2] = f2bf(t0.z); pb[3] = f2bf(t0.w);
      pb[4] = f2bf(t1.x); pb[5] = f2bf(t1.y); pb[6] = f2bf(t1.z); pb[7] = f2bf(t1.w);
    }
    *(bf16x8*)&tfb[dst] = pb;
  }

  // (c) t_region pass: dequeue write (nt scalar stores; dst only 4B-aligned)
  // + per-row teacher softmax stats. Source rows are re-read by the loss
  // gather -> CACHED loads.
  const float4 cg4 = *(const float4*)(center_grid + lane * 4);
  for (int r = wave; r < NR; r += 8) {
    const float* src = use ? (qg + (size_t)r * Dv)
                           : (t_region_out + ((size_t)bt * NR + r) * Dv);
    float4 v = *(const float4*)(src + lane * 4);
    float* o = out_tr + ((size_t)bt * NR + r) * Dv + lane * 4;
    __builtin_nontemporal_store(v.x, o);
    __builtin_nontemporal_store(v.y, o + 1);
    __builtin_nontemporal_store(v.z, o + 2);
    __builtin_nontemporal_store(v.w, o + 3);
    float x0 = (v.x - cg4.x) * INV_TAU, x1 = (v.y - cg4.y) * INV_TAU;
    float x2 = (v.z - cg4.z) * INV_TAU, x3 = (v.w - cg4.w) * INV_TAU;
    float m = wave_max(fmaxf(fmaxf(x0, x1), fmaxf(x2, x3)));
    float e = wave_sum(expf(x0 - m) + expf(x1 - m) + expf(x2 - m) + expf(x3 - m));
    if (lane == 0) { stats[r * 2] = m; stats[r * 2 + 1] = e; }
  }

  // (d) cls KL term (wave 7; wave-local)
  if (wave == 7) {
    const float* tcsrc = use ? (queue_all + qoff * Dv) : (t_cls_out + (size_t)bt * Dv);
    float4 t4 = *(const float4*)(tcsrc + lane * 4);
    float* otc = out_tc + (size_t)bt * Dv + lane * 4;
    __builtin_nontemporal_store(t4.x, otc);
    __builtin_nontemporal_store(t4.y, otc + 1);
    __builtin_nontemporal_store(t4.z, otc + 2);
    __builtin_nontemporal_store(t4.w, otc + 3);
    float4 c4 = *(const float4*)(center + lane * 4);
    float x0 = (t4.x - c4.x) * INV_TAU, x1 = (t4.y - c4.y) * INV_TAU;
    float x2 = (t4.z - c4.z) * INV_TAU, x3 = (t4.w - c4.w) * INV_TAU;
    float M = wave_max(fmaxf(fmaxf(x0, x1), fmaxf(x2, x3)));
    float e0 = expf(x0 - M), e1 = expf(x1 - M), e2 = expf(x2 - M), e3 = expf(x3 - M);
    float S = wave_sum(e0 + e1 + e2 + e3);
    f32x4 s4 = ntld4(s_cls_out + (size_t)bs * Dv + lane * 4);
    float z0 = s4.x * INV_TAU, z1 = s4.y * INV_TAU;
    float z2 = s4.z * INV_TAU, z3 = s4.w * INV_TAU;
    float M2 = wave_max(fmaxf(fmaxf(z0, z1), fmaxf(z2, z3)));
    float S2 = wave_sum(expf(z0 - M2) + expf(z1 - M2) + expf(z2 - M2) + expf(z3 - M2));
    float lse = M2 + logf(S2);
    float cv = 0.5f * wave_sum(e0 * (lse - z0) + e1 * (lse - z1) +
                               e2 * (lse - z2) + e3 * (lse - z3)) / S;
    if (lane == 0) cls_s = cv;
  }
  __syncthreads();

  // ---- teacher row inverse norms (only m < NR used by argmax) ----
  for (int r = wave; r < NR; r += 8) {
    const int ch = (lane >> 1) ^ (r & 7);
    const unsigned short* p = &tfb[r * Dv + ch * 8 + (lane & 1) * 4];
    float a0 = bf2f(p[0]), a1 = bf2f(p[1]), a2 = bf2f(p[2]), a3 = bf2f(p[3]);
    float ss = wave_sum(a0 * a0 + a1 * a1 + a2 * a2 + a3 * a3);
    if (lane == 0) rinv[r] = 1.0f / fmaxf(sqrtf(ss), 1e-12f);
  }
  __syncthreads();

  // ---- MFMA sim, 8-wave split: wave = (half m-block) x (A row-block) ----
  {
    const int half = wave >> 2, wr = wave & 3;
    f32x4 acc[2];
    acc[0] = (f32x4){0.f, 0.f, 0.f, 0.f};
    acc[1] = (f32x4){0.f, 0.f, 0.f, 0.f};
    const int rsel = lane & 15, g = lane >> 4, rsw = lane & 7;
    const int rowA = (wr << 4) + rsel;
#pragma unroll
    for (int kk = 0; kk < 8; kk++) {
      const int ch = (kk * 4 + g) ^ rsw;  // rowA&7 == rowB&7 == lane&7
      bf16x8 a = *(const bf16x8*)&sfb[rowA * Dv + (ch << 3)];
#pragma unroll
      for (int mh = 0; mh < 2; mh++) {
        const int mb = half * 2 + mh;
        bf16x8 b = *(const bf16x8*)&tfb[((mb << 4) + rsel) * Dv + (ch << 3)];
        acc[mh] = __builtin_amdgcn_mfma_f32_16x16x32_bf16(a, b, acc[mh], 0, 0, 0);
      }
    }
    float bv[4] = {-INFINITY, -INFINITY, -INFINITY, -INFINITY};
    int bm[4] = {999, 999, 999, 999};
#pragma unroll
    for (int mh = 0; mh < 2; mh++) {
      const int m = ((half * 2 + mh) << 4) + rsel;
      if (m < NR) {
        const float rv = rinv[m];
#pragma unroll
        for (int r = 0; r < 4; r++) {
          float s = acc[mh][r] * rv;
          if (s > bv[r]) { bv[r] = s; bm[r] = m; }  // m ascending -> first max
        }
      }
    }
#pragma unroll
    for (int o = 1; o < 16; o <<= 1) {
#pragma unroll
      for (int r = 0; r < 4; r++) {
        float ov = __shfl_xor(bv[r], o);
        int om = __shfl_xor(bm[r], o);
        if (ov > bv[r] || (ov == bv[r] && om < bm[r])) { bv[r] = ov; bm[r] = om; }
      }
    }
    if (rsel == 0) {
#pragma unroll
      for (int r = 0; r < 4; r++) {
        const int n = (wr << 4) + (g << 2) + r;
        cand_v[half][n] = bv[r];
        cand_m[half][n] = bm[r];
      }
    }
  }
  __syncthreads();

  // ---- loss rows: y/lse in regs; inline half-combine (tie -> half 0);
  //      teacher gather via cached path (rows touched in phase c) ----
  float4 tv[7];
  int msj[7];
#pragma unroll
  for (int j = 0; j < 7; j++) {
    const int n = wave + 8 * j;
    if (n < NR) {
      const int ms = (cand_v[1][n] > cand_v[0][n]) ? cand_m[1][n] : cand_m[0][n];
      msj[j] = ms;
      const float* trow = use ? (qg + (size_t)ms * Dv)
                              : (t_region_out + ((size_t)bt * NR + ms) * Dv);
      tv[j] = *(const float4*)(trow + lane * 4);
    }
  }
  float gacc = 0.f;
#pragma unroll
  for (int j = 0; j < 7; j++) {
    const int n = wave + 8 * j;
    if (n < NR) {
      const int ms = msj[j];
      const float4 v4 = tv[j];
      const f32x4 y4 = yv[j];
      const float lse = lsev[j];
      float x0 = (v4.x - cg4.x) * INV_TAU, x1 = (v4.y - cg4.y) * INV_TAU;
      float x2 = (v4.z - cg4.z) * INV_TAU, x3 = (v4.w - cg4.w) * INV_TAU;
      float tmax = stats[ms * 2], tsum = stats[ms * 2 + 1];
      float part = wave_sum(expf(x0 - tmax) * (lse - y4.x) +
                            expf(x1 - tmax) * (lse - y4.y) +
                            expf(x2 - tmax) * (lse - y4.z) +
                            expf(x3 - tmax) * (lse - y4.w));
      gacc += part / tsum;
    }
  }
  if (lane == 0) red[wave] = gacc;
  __syncthreads();
  if (tid == 0) {
    float s = red[0] + red[1] + red[2] + red[3] +
              red[4] + red[5] + red[6] + red[7];
    block_part[bt] = cls_s + (0.5f / 49.0f) * s;
  }
}

// ---------------------------------------------------------------------------
// k4: deterministic final reduction, single wave. out[0] = sum/512
// ---------------------------------------------------------------------------
__global__ __launch_bounds__(64) void k4_final(const float* __restrict__ block_part,
                                               float* __restrict__ out) {
  const int lane = threadIdx.x;
  float a = 0.f;
#pragma unroll
  for (int j = 0; j < 8; j++) a += block_part[lane + 64 * j];
  a = wave_sum(a);
  if (lane == 0) out[0] = a * (1.0f / 512.0f);
}

extern "C" void kernel_launch(void* const* d_in, const int* in_sizes, int n_in,
                              void* d_out, int out_size, void* d_ws, size_t ws_size,
                              hipStream_t stream) {
  (void)in_sizes; (void)n_in; (void)out_size; (void)ws_size;
  const float* s_cls_out      = (const float*)d_in[0];
  const float* s_region_out   = (const float*)d_in[1];
  const float* s_fea          = (const float*)d_in[2];
  const float* t_cls_out      = (const float*)d_in[3];
  const float* t_region_out   = (const float*)d_in[4];
  const float* t_fea          = (const float*)d_in[5];
  const float* queue_all      = (const float*)d_in[6];
  const float* queue_grid_all = (const float*)d_in[7];
  const float* center         = (const float*)d_in[8];
  const float* center_grid    = (const float*)d_in[9];
  const int* concept_idx      = (const int*)d_in[10];
  const int* pos_idx          = (const int*)d_in[11];
  const unsigned char* use_q  = (const unsigned char*)d_in[12];

  float* out    = (float*)d_out;
  float* out_tc = out + 1;                 // 512*256
  float* out_tr = out + 1 + B2v * Dv;      // 25088*256

  float* block_part = (float*)d_ws;        // 512 floats

  kmain<<<B2v, 512, 0, stream>>>(s_cls_out, s_region_out, s_fea, t_cls_out,
                                 t_region_out, t_fea, queue_all, queue_grid_all,
                                 center, center_grid, concept_idx, pos_idx,
                                 use_q, out_tc, out_tr, block_part);
  k4_final<<<1, 64, 0, stream>>>(block_part, out);
}

// Round 9
// 37.762 us; speedup vs baseline: 1.0954x; 1.0954x over previous
//
#include <hip/hip_runtime.h>
#include <math.h>

namespace {
constexpr int B2v = 512;
constexpr int NR  = 49;     // regions per view
constexpr int NP  = 64;     // padded rows for MFMA tile
constexpr int Dv  = 256;    // feature dim
constexpr int KQ  = 128;    // queue K
constexpr float INV_TAU     = 25.0f;  // 1/0.04
constexpr float INV_TAU_STU = 10.0f;  // 1/0.1
}

typedef __attribute__((ext_vector_type(8))) short bf16x8;
typedef __attribute__((ext_vector_type(4))) float f32x4;

__device__ __forceinline__ float wave_max(float v) {
  for (int o = 32; o; o >>= 1) v = fmaxf(v, __shfl_xor(v, o));
  return v;
}
__device__ __forceinline__ float wave_sum(float v) {
  for (int o = 32; o; o >>= 1) v += __shfl_xor(v, o);
  return v;
}
__device__ __forceinline__ short f2bf(float x) {  // RNE fp32->bf16
  unsigned u = __float_as_uint(x);
  u = u + 0x7FFFu + ((u >> 16) & 1u);
  return (short)(u >> 16);
}
__device__ __forceinline__ float bf2f(unsigned short h) {
  return __uint_as_float(((unsigned)h) << 16);
}

// ---------------------------------------------------------------------------
// kmain: one 512-thread block per teacher batch bt (student bs = bt ^ 256).
// 8 waves, 2 blocks/CU. Key identity: sum_d p[m][d] = 1, so the grid term is
// lse_n - dot(p[ms(n)], y[n]). Teacher p-rows are computed in the single
// first-pass stream (held in regs), parked in LDS AFTER the sim-MFMA by
// reusing the then-dead sfb/tfb 64KB region (49x256 fp32 = 50KB). The loss
// phase is pure LDS — no second global gather, no second exp pass.
// ---------------------------------------------------------------------------
__global__ __launch_bounds__(512, 4) void kmain(
    const float* __restrict__ s_cls_out,
    const float* __restrict__ s_region_out,
    const float* __restrict__ s_fea,
    const float* __restrict__ t_cls_out,
    const float* __restrict__ t_region_out,
    const float* __restrict__ t_fea,
    const float* __restrict__ queue_all,
    const float* __restrict__ queue_grid_all,
    const float* __restrict__ center,
    const float* __restrict__ center_grid,
    const int* __restrict__ concept_idx,
    const int* __restrict__ pos_idx,
    const unsigned char* __restrict__ uq,
    float* __restrict__ out_tc,
    float* __restrict__ out_tr,
    float* __restrict__ block_part) {
  __shared__ __align__(16) unsigned char lds_raw[NP * Dv * 2 * 2];  // 64 KB
  __shared__ float rinv[NP];
  __shared__ float cand_v[2][NP];
  __shared__ int   cand_m[2][NP];
  __shared__ float red[8];
  __shared__ float cls_s;

  unsigned short* sfb = (unsigned short*)lds_raw;                    // 32 KB
  unsigned short* tfb = (unsigned short*)(lds_raw + NP * Dv * 2);    // 32 KB
  float* p32 = (float*)lds_raw;  // 49*256 fp32 = 50 KB, valid after MFMA

  const int bt = blockIdx.x, bs = bt ^ 256;
  const int tid = threadIdx.x, lane = tid & 63, wave = tid >> 6;

  // ---- hoisted scalar/index loads ----
  const int ci = concept_idx[bt], pi = pos_idx[bt];
  const uint2 w2 = ((const uint2*)uq)[lane];  // 512 B, legal in both layouts
  const float* sfsrc = s_fea + (size_t)bs * NR * Dv;

  // (a1) stage s-side bf16 tile (16B-chunk XOR swizzle: c ^= r&7)
  for (int q = tid; q < NP * 32; q += 512) {
    const int r = q >> 5, c = q & 31;
    const int dst = r * Dv + ((c ^ (r & 7)) << 3);
    bf16x8 pa = {0, 0, 0, 0, 0, 0, 0, 0};
    if (r < NR) {
      const float* ps = sfsrc + (size_t)r * Dv + c * 8;
      float4 s0 = *(const float4*)ps, s1 = *(const float4*)(ps + 4);
      pa[0] = f2bf(s0.x); pa[1] = f2bf(s0.y); pa[2] = f2bf(s0.z); pa[3] = f2bf(s0.w);
      pa[4] = f2bf(s1.x); pa[5] = f2bf(s1.y); pa[6] = f2bf(s1.z); pa[7] = f2bf(s1.w);
    }
    *(bf16x8*)&sfb[dst] = pa;
  }

  // (b) s_region y rows -> registers (wave-interleaved n), lse per row
  float4 yv[7];
  float lsev[7];
#pragma unroll
  for (int j = 0; j < 7; j++) {
    const int n = wave + 8 * j;
    if (n < NR) {
      float4 y4 = *(const float4*)(s_region_out + ((size_t)bs * NR + n) * Dv + lane * 4);
      y4.x *= INV_TAU_STU; y4.y *= INV_TAU_STU;
      y4.z *= INV_TAU_STU; y4.w *= INV_TAU_STU;
      float smax = wave_max(fmaxf(fmaxf(y4.x, y4.y), fmaxf(y4.z, y4.w)));
      float ssum = wave_sum(expf(y4.x - smax) + expf(y4.y - smax) +
                            expf(y4.z - smax) + expf(y4.w - smax));
      yv[j] = y4;
      lsev[j] = smax + logf(ssum);
    }
  }

  // ---- per-wave use_queue layout detection (no barrier) ----
  const bool isbool = __any(((w2.x | w2.y) & 0xFFFFFF00u) != 0) != 0;
  const int uqv = isbool ? (int)uq[bt] : ((const int*)uq)[bt];
  const bool use = uqv != 0;
  const size_t qoff = (size_t)ci * KQ + (size_t)pi;
  const float* qg = queue_grid_all + qoff * (size_t)(2 * NR) * Dv;
  const float* tfsrc = use ? (qg + (size_t)NR * Dv) : (t_fea + (size_t)bt * NR * Dv);

  // (a2) stage t-side bf16 tile
  for (int q = tid; q < NP * 32; q += 512) {
    const int r = q >> 5, c = q & 31;
    const int dst = r * Dv + ((c ^ (r & 7)) << 3);
    bf16x8 pb = {0, 0, 0, 0, 0, 0, 0, 0};
    if (r < NR) {
      const float* pt = tfsrc + (size_t)r * Dv + c * 8;
      float4 t0 = *(const float4*)pt, t1 = *(const float4*)(pt + 4);
      pb[0] = f2bf(t0.x); pb[1] = f2bf(t0.y); pb[2] = f2bf(t0.z); pb[3] = f2bf(t0.w);
      pb[4] = f2bf(t1.x); pb[5] = f2bf(t1.y); pb[6] = f2bf(t1.z); pb[7] = f2bf(t1.w);
    }
    *(bf16x8*)&tfb[dst] = pb;
  }

  // (c1) t_region pass: read rows ONCE -> out_tr write + teacher softmax
  // p-values straight into registers (stats are wave-local).
  const float4 cg4 = *(const float4*)(center_grid + lane * 4);
  float4 pv[7];
#pragma unroll
  for (int j = 0; j < 7; j++) {
    const int r = wave + 8 * j;
    if (r < NR) {
      const float* src = use ? (qg + (size_t)r * Dv)
                             : (t_region_out + ((size_t)bt * NR + r) * Dv);
      float4 v = *(const float4*)(src + lane * 4);
      float* o = out_tr + ((size_t)bt * NR + r) * Dv + lane * 4;  // 4B-aligned
      o[0] = v.x; o[1] = v.y; o[2] = v.z; o[3] = v.w;
      float x0 = (v.x - cg4.x) * INV_TAU, x1 = (v.y - cg4.y) * INV_TAU;
      float x2 = (v.z - cg4.z) * INV_TAU, x3 = (v.w - cg4.w) * INV_TAU;
      float m = wave_max(fmaxf(fmaxf(x0, x1), fmaxf(x2, x3)));
      float e0 = expf(x0 - m), e1 = expf(x1 - m);
      float e2 = expf(x2 - m), e3 = expf(x3 - m);
      float inv = 1.0f / wave_sum(e0 + e1 + e2 + e3);
      pv[j] = make_float4(e0 * inv, e1 * inv, e2 * inv, e3 * inv);
    }
  }

  // (d) cls KL term (wave 7; wave-local)
  if (wave == 7) {
    const float* tcsrc = use ? (queue_all + qoff * Dv) : (t_cls_out + (size_t)bt * Dv);
    float4 t4 = *(const float4*)(tcsrc + lane * 4);
    float* otc = out_tc + (size_t)bt * Dv + lane * 4;  // 4B-aligned
    otc[0] = t4.x; otc[1] = t4.y; otc[2] = t4.z; otc[3] = t4.w;
    float4 c4 = *(const float4*)(center + lane * 4);
    float x0 = (t4.x - c4.x) * INV_TAU, x1 = (t4.y - c4.y) * INV_TAU;
    float x2 = (t4.z - c4.z) * INV_TAU, x3 = (t4.w - c4.w) * INV_TAU;
    float M = wave_max(fmaxf(fmaxf(x0, x1), fmaxf(x2, x3)));
    float e0 = expf(x0 - M), e1 = expf(x1 - M), e2 = expf(x2 - M), e3 = expf(x3 - M);
    float S = wave_sum(e0 + e1 + e2 + e3);
    float4 s4 = *(const float4*)(s_cls_out + (size_t)bs * Dv + lane * 4);
    float z0 = s4.x * INV_TAU, z1 = s4.y * INV_TAU;
    float z2 = s4.z * INV_TAU, z3 = s4.w * INV_TAU;
    float M2 = wave_max(fmaxf(fmaxf(z0, z1), fmaxf(z2, z3)));
    float S2 = wave_sum(expf(z0 - M2) + expf(z1 - M2) + expf(z2 - M2) + expf(z3 - M2));
    float lse = M2 + logf(S2);
    float cv = 0.5f * wave_sum(e0 * (lse - z0) + e1 * (lse - z1) +
                               e2 * (lse - z2) + e3 * (lse - z3)) / S;
    if (lane == 0) cls_s = cv;
  }
  __syncthreads();

  // ---- teacher row inverse norms (from staged bf16) ----
  for (int r = wave; r < NR; r += 8) {
    const int ch = (lane >> 1) ^ (r & 7);
    const unsigned short* p = &tfb[r * Dv + ch * 8 + (lane & 1) * 4];
    float a0 = bf2f(p[0]), a1 = bf2f(p[1]), a2 = bf2f(p[2]), a3 = bf2f(p[3]);
    float ss = wave_sum(a0 * a0 + a1 * a1 + a2 * a2 + a3 * a3);
    if (lane == 0) rinv[r] = 1.0f / fmaxf(sqrtf(ss), 1e-12f);
  }
  __syncthreads();

  // ---- MFMA sim, 8-wave split: wave = (half m-block) x (A row-block) ----
  {
    const int half = wave >> 2, wr = wave & 3;
    f32x4 acc[2];
    acc[0] = (f32x4){0.f, 0.f, 0.f, 0.f};
    acc[1] = (f32x4){0.f, 0.f, 0.f, 0.f};
    const int rsel = lane & 15, g = lane >> 4, rsw = lane & 7;
    const int rowA = (wr << 4) + rsel;
#pragma unroll
    for (int kk = 0; kk < 8; kk++) {
      const int ch = (kk * 4 + g) ^ rsw;  // rowA&7 == rowB&7 == lane&7
      bf16x8 a = *(const bf16x8*)&sfb[rowA * Dv + (ch << 3)];
#pragma unroll
      for (int mh = 0; mh < 2; mh++) {
        const int mb = half * 2 + mh;
        bf16x8 b = *(const bf16x8*)&tfb[((mb << 4) + rsel) * Dv + (ch << 3)];
        acc[mh] = __builtin_amdgcn_mfma_f32_16x16x32_bf16(a, b, acc[mh], 0, 0, 0);
      }
    }
    float bv[4] = {-INFINITY, -INFINITY, -INFINITY, -INFINITY};
    int bm[4] = {999, 999, 999, 999};
#pragma unroll
    for (int mh = 0; mh < 2; mh++) {
      const int m = ((half * 2 + mh) << 4) + rsel;
      if (m < NR) {
        const float rv = rinv[m];
#pragma unroll
        for (int r = 0; r < 4; r++) {
          float s = acc[mh][r] * rv;
          if (s > bv[r]) { bv[r] = s; bm[r] = m; }  // m ascending -> first max
        }
      }
    }
#pragma unroll
    for (int o = 1; o < 16; o <<= 1) {
#pragma unroll
      for (int r = 0; r < 4; r++) {
        float ov = __shfl_xor(bv[r], o);
        int om = __shfl_xor(bm[r], o);
        if (ov > bv[r] || (ov == bv[r] && om < bm[r])) { bv[r] = ov; bm[r] = om; }
      }
    }
    if (rsel == 0) {
#pragma unroll
      for (int r = 0; r < 4; r++) {
        const int n = (wr << 4) + (g << 2) + r;
        cand_v[half][n] = bv[r];
        cand_m[half][n] = bm[r];
      }
    }
  }
  __syncthreads();  // all MFMA reads of sfb/tfb done -> region reusable

  // ---- park p-rows in LDS (overwrites dead sfb/tfb region) ----
#pragma unroll
  for (int j = 0; j < 7; j++) {
    const int r = wave + 8 * j;
    if (r < NR) *(float4*)&p32[r * 256 + lane * 4] = pv[j];
  }
  __syncthreads();

  // ---- loss rows: lse_n - dot(p[ms(n)], y[n]); pure LDS + registers ----
  float gacc = 0.f;
#pragma unroll
  for (int j = 0; j < 7; j++) {
    const int n = wave + 8 * j;
    if (n < NR) {
      const int ms = (cand_v[1][n] > cand_v[0][n]) ? cand_m[1][n] : cand_m[0][n];
      float4 pm = *(const float4*)&p32[ms * 256 + lane * 4];
      float d = pm.x * yv[j].x + pm.y * yv[j].y + pm.z * yv[j].z + pm.w * yv[j].w;
      d = wave_sum(d);
      gacc += lsev[j] - d;
    }
  }
  if (lane == 0) red[wave] = gacc;
  __syncthreads();
  if (tid == 0) {
    float s = red[0] + red[1] + red[2] + red[3] +
              red[4] + red[5] + red[6] + red[7];
    block_part[bt] = cls_s + (0.5f / 49.0f) * s;
  }
}

// ---------------------------------------------------------------------------
// k4: deterministic final reduction, single wave. out[0] = sum/512
// ---------------------------------------------------------------------------
__global__ __launch_bounds__(64) void k4_final(const float* __restrict__ block_part,
                                               float* __restrict__ out) {
  const int lane = threadIdx.x;
  float a = 0.f;
#pragma unroll
  for (int j = 0; j < 8; j++) a += block_part[lane + 64 * j];
  a = wave_sum(a);
  if (lane == 0) out[0] = a * (1.0f / 512.0f);
}

extern "C" void kernel_launch(void* const* d_in, const int* in_sizes, int n_in,
                              void* d_out, int out_size, void* d_ws, size_t ws_size,
                              hipStream_t stream) {
  (void)in_sizes; (void)n_in; (void)out_size; (void)ws_size;
  const float* s_cls_out      = (const float*)d_in[0];
  const float* s_region_out   = (const float*)d_in[1];
  const float* s_fea          = (const float*)d_in[2];
  const float* t_cls_out      = (const float*)d_in[3];
  const float* t_region_out   = (const float*)d_in[4];
  const float* t_fea          = (const float*)d_in[5];
  const float* queue_all      = (const float*)d_in[6];
  const float* queue_grid_all = (const float*)d_in[7];
  const float* center         = (const float*)d_in[8];
  const float* center_grid    = (const float*)d_in[9];
  const int* concept_idx      = (const int*)d_in[10];
  const int* pos_idx          = (const int*)d_in[11];
  const unsigned char* use_q  = (const unsigned char*)d_in[12];

  float* out    = (float*)d_out;
  float* out_tc = out + 1;                 // 512*256
  float* out_tr = out + 1 + B2v * Dv;      // 25088*256

  float* block_part = (float*)d_ws;        // 512 floats

  kmain<<<B2v, 512, 0, stream>>>(s_cls_out, s_region_out, s_fea, t_cls_out,
                                 t_region_out, t_fea, queue_all, queue_grid_all,
                                 center, center_grid, concept_idx, pos_idx,
                                 use_q, out_tc, out_tr, block_part);
  k4_final<<<1, 64, 0, stream>>>(block_part, out);
}